// Round 15
// baseline (624.916 us; speedup 1.0000x reference)
//
#include <hip/hip_runtime.h>

typedef __attribute__((ext_vector_type(8))) short short8;
typedef __attribute__((ext_vector_type(4))) float f32x4;
typedef unsigned short ushort_t;
typedef unsigned int uint32;

// ---------- constants ----------
#define N0 30000
#define N1 90000
#define N2 60000
#define P0 30208   // 236*128, 472*64
#define S1OFF 30208
#define S2OFF 120320
#define MPAD 180352
#define MT0 236
#define MT_ALL 1409
#define MT64Y 2818  // MPAD/64
#define NE0 960000
#define NE1 180000
#define NE2 180000
#define NNZ_ALL 1320000
#define CSTRIDE 30720  // per-level cur/rowPtr stride (>= N0+1)

__device__ __forceinline__ float bf2f(ushort_t u) {
    union { uint32 i; float f; } v; v.i = ((uint32)u) << 16; return v.f;
}
__device__ __forceinline__ ushort_t f2bf(float f) {
    union { float f; uint32 i; } v; v.f = f;
    uint32 x = v.i;
    x += ((x >> 16) & 1u) + 0x7FFFu;   // RNE
    return (ushort_t)(x >> 16);
}

// ---------- prep: weights -> bf16 transposed layouts ----------
__global__ __launch_bounds__(256) void prep_w(const float* __restrict__ W1,
                                              const float* __restrict__ Wagg,
                                              const float* __restrict__ bagg,
                                              ushort_t* __restrict__ W1t,   // [4][128][256]
                                              ushort_t* __restrict__ Wgt,   // [4][3][128][128]
                                              ushort_t* __restrict__ WgtC,  // [128][512]
                                              float* __restrict__ bsum) {   // [128]
    int idx = blockIdx.x * blockDim.x + threadIdx.x;
    if (idx < 131072) {  // W1t[h][n][k] = W1[h][k][n]
        int h = idx >> 15, rem = idx & 32767, n = rem >> 8, k = rem & 255;
        W1t[idx] = f2bf(W1[((size_t)h * 256 + k) * 128 + n]);
    }
    if (idx < 196608) {  // Wgt[h][l][n][k] = Wagg[h][(l+1)*128+k][n]
        int h = idx / 49152, rem = idx % 49152;
        int l = rem / 16384, rem2 = rem % 16384, n = rem2 >> 7, k = rem2 & 127;
        Wgt[idx] = f2bf(Wagg[((size_t)h * 512 + (l + 1) * 128 + k) * 128 + n]);
    }
    if (idx < 65536) {   // WgtC[n][h*128+k] = Wagg[h][k][n]  (block 0)
        int n = idx >> 9, kk = idx & 511, h = kk >> 7, k = kk & 127;
        WgtC[idx] = f2bf(Wagg[((size_t)h * 512 + k) * 128 + n]);
    }
    if (idx < 128) {
        float s = 0.f;
        #pragma unroll
        for (int h = 0; h < 4; ++h) s += bagg[h * 128 + idx];
        bsum[idx] = s;
    }
}

// ---------- CSR build (merged across levels) ----------
__global__ __launch_bounds__(256) void csr_zero(int* __restrict__ cur) {
    int i = blockIdx.x * blockDim.x + threadIdx.x;
    if (i < 3 * CSTRIDE) cur[i] = 0;
}

__global__ __launch_bounds__(256) void csr_hist_all(const int* __restrict__ rows0,
                                                    const int* __restrict__ rows1,
                                                    const int* __restrict__ rows2,
                                                    int* __restrict__ cur) {
    int i = blockIdx.x * blockDim.x + threadIdx.x;
    if (i < NE0)                 atomicAdd(cur + rows0[i], 1);
    else if (i < NE0 + NE1)      atomicAdd(cur + CSTRIDE + rows1[i - NE0], 1);
    else if (i < NNZ_ALL)        atomicAdd(cur + 2 * CSTRIDE + rows2[i - NE0 - NE1], 1);
}

__global__ __launch_bounds__(1024) void csr_scan(int* __restrict__ curA,
                                                 int* __restrict__ rowPtrA,
                                                 int nE0, int nE1, int nE2) {
    __shared__ int ssum[1024];
    const int b = blockIdx.x;
    int* cur = curA + b * CSTRIDE;
    int* rowPtr = rowPtrA + b * CSTRIDE;
    const int nE = (b == 0) ? nE0 : (b == 1 ? nE1 : nE2);
    const int t = threadIdx.x;
    const int base = t * 30;
    int loc[30];
    int s = 0;
    #pragma unroll
    for (int i = 0; i < 30; ++i) {
        int r = base + i;
        int v = (r < N0) ? cur[r] : 0;
        loc[i] = s; s += v;
    }
    ssum[t] = s;
    __syncthreads();
    for (int off = 1; off < 1024; off <<= 1) {
        int v = (t >= off) ? ssum[t - off] : 0;
        __syncthreads();
        ssum[t] += v;
        __syncthreads();
    }
    int carry = (t == 0) ? 0 : ssum[t - 1];
    #pragma unroll
    for (int i = 0; i < 30; ++i) {
        int r = base + i;
        if (r < N0) {
            int p = carry + loc[i];
            rowPtr[r] = p;
            cur[r] = p;
        }
    }
    if (t == 0) rowPtr[N0] = nE;
}

__global__ __launch_bounds__(256) void csr_scatter_all(const int* __restrict__ rows0,
                                                       const int* __restrict__ cols0,
                                                       const int* __restrict__ rows1,
                                                       const int* __restrict__ cols1,
                                                       const int* __restrict__ rows2,
                                                       const int* __restrict__ cols2,
                                                       int* __restrict__ cur,
                                                       int* __restrict__ srtCg) {
    int i = blockIdx.x * blockDim.x + threadIdx.x;
    if (i < NE0) {
        int pos = atomicAdd(cur + rows0[i], 1);
        srtCg[pos] = cols0[i];
    } else if (i < NE0 + NE1) {
        int j = i - NE0;
        int pos = atomicAdd(cur + CSTRIDE + rows1[j], 1);
        srtCg[NE0 + pos] = S1OFF + cols1[j];
    } else if (i < NNZ_ALL) {
        int j = i - NE0 - NE1;
        int pos = atomicAdd(cur + 2 * CSTRIDE + rows2[j], 1);
        srtCg[NE0 + NE1 + pos] = S2OFF + cols2[j];
    }
}

// ---------- Y = relu(X @ W1 + b1): r12-proven ----------
// grid 2818; 256 thr = 4 waves, each 64 rows x 64 consecutive cols of one head.
// As[64][256] swizzled (staged ONCE); Bs[2][128][40] per-kt head-pair staging.
__global__ __launch_bounds__(256, 3)
void gemm_y(const float* __restrict__ x0, const float* __restrict__ x1,
            const float* __restrict__ x2,
            const ushort_t* __restrict__ W1t, const float* __restrict__ b1,
            ushort_t* __restrict__ Y)
{
    __shared__ ushort_t As[64 * 256];
    __shared__ ushort_t Bs[2][128 * 40];
    const int tid = threadIdx.x;
    const int lane = tid & 63;
    const int wn = tid >> 6;                 // 0..3: col group
    const int l15 = lane & 15, lg = lane >> 4;
    const int r0 = blockIdx.x * 64;

    const float* src; int jbase, nreal;
    if (r0 < P0)          { src = x0; jbase = r0;         nreal = N0; }
    else if (r0 < S2OFF)  { src = x1; jbase = r0 - S1OFF; nreal = N1; }
    else                  { src = x2; jbase = r0 - S2OFF; nreal = N2; }

    // stage As once: 64 rows x 32 chunks (8 bf16 each), swizzled c^(row&7)
    #pragma unroll
    for (int p = 0; p < 8; ++p) {
        int chunk = tid + p * 256;
        int row = chunk >> 5, c = chunk & 31;
        int j = jbase + row;
        ushort_t o[8] __attribute__((aligned(16)));
        if (j < nreal) {
            const float4 v0 = *(const float4*)(src + (size_t)j * 256 + c * 8);
            const float4 v1 = *(const float4*)(src + (size_t)j * 256 + c * 8 + 4);
            o[0] = f2bf(v0.x); o[1] = f2bf(v0.y); o[2] = f2bf(v0.z); o[3] = f2bf(v0.w);
            o[4] = f2bf(v1.x); o[5] = f2bf(v1.y); o[6] = f2bf(v1.z); o[7] = f2bf(v1.w);
        } else {
            #pragma unroll
            for (int i = 0; i < 8; ++i) o[i] = 0;
        }
        *(uint4*)(As + row * 256 + ((c ^ (row & 7)) << 3)) = *(const uint4*)o;
    }

    const int hh = wn >> 1;                  // head within pair (wave-uniform)
    const int nbase = (wn & 1) * 64;         // col base within head

    #pragma unroll 1
    for (int hp = 0; hp < 2; ++hp) {
        f32x4 acc[4][4] = {};
        #pragma unroll 1
        for (int kt = 0; kt < 256; kt += 32) {
            __syncthreads();   // previous readers done (covers As staging on iter 0)
            // stage Bs for heads hp*2, hp*2+1: 1024 chunks, 4/thread
            #pragma unroll
            for (int q = 0; q < 4; ++q) {
                int id = tid + q * 256;
                int bh = id >> 9, rem = id & 511;
                int n = rem >> 2, c = rem & 3;
                *(uint4*)(Bs[bh] + n * 40 + c * 8) =
                    *(const uint4*)(W1t + (hp * 2 + bh) * 32768 + n * 256 + kt + c * 8);
            }
            __syncthreads();

            short8 af[4], bf[4];
            #pragma unroll
            for (int m = 0; m < 4; ++m) {
                int row = m * 16 + l15;
                af[m] = *(const short8*)(As + row * 256 + ((((kt >> 3) + lg) ^ (row & 7)) << 3));
            }
            #pragma unroll
            for (int nf = 0; nf < 4; ++nf) {
                int nrow = nbase + nf * 16 + l15;
                bf[nf] = *(const short8*)(Bs[hh] + nrow * 40 + lg * 8);
            }
            #pragma unroll
            for (int m = 0; m < 4; ++m)
                #pragma unroll
                for (int nf = 0; nf < 4; ++nf)
                    acc[m][nf] = __builtin_amdgcn_mfma_f32_16x16x32_bf16(af[m], bf[nf], acc[m][nf], 0, 0, 0);
        }
        // epilogue: wave writes 64 consecutive cols of head h -> full 128B lines
        int h = hp * 2 + hh;
        #pragma unroll
        for (int nf = 0; nf < 4; ++nf) {
            int col = nbase + nf * 16 + l15;
            float bb = b1[h * 128 + col];
            #pragma unroll
            for (int m = 0; m < 4; ++m)
            #pragma unroll
            for (int j = 0; j < 4; ++j) {
                int row = r0 + m * 16 + lg * 4 + j;
                float v = acc[m][nf][j] + bb;
                v = v > 0.f ? v : 0.f;
                Y[(size_t)row * 512 + h * 128 + col] = f2bf(v);
            }
        }
    }
}

// ---------- fused z-projection (in place on Y) + attention coefficients ----------
// r12-proven: grid (MT_ALL, 4 heads); K=128 fully staged, 2 barriers, 64 MFMAs;
// coef dots read staged pre-overwrite As, plain stores.
__global__ __launch_bounds__(256) void gemm_z(ushort_t* Y,
                                              const ushort_t* __restrict__ Wgt,
                                              const float* __restrict__ a1w,
                                              const float* __restrict__ a1b,
                                              const float* __restrict__ a2w,
                                              const float* __restrict__ a2b,
                                              float* __restrict__ a1o,   // [4][P0]
                                              float* __restrict__ a2o) { // [4][MPAD]
    __shared__ ushort_t As[128 * 136];
    __shared__ ushort_t Bs[128 * 136];
    __shared__ float a1wS[128], a2wS[128];
    const int tid = threadIdx.x;
    const int h = blockIdx.y;
    const int r0 = blockIdx.x * 128;
    const int l = (r0 < P0) ? 0 : (r0 < S2OFF ? 1 : 2);
    const ushort_t* B = Wgt + ((h * 3 + l) << 14);
    ushort_t* A = Y + (size_t)h * 128;   // col block of head h, ld 512

    if (tid < 128) {
        a1wS[tid] = a1w[h * 128 + tid];
        a2wS[tid] = a2w[h * 128 + tid];
    }
    #pragma unroll
    for (int c = 0; c < 8; ++c) {
        int idx = tid + c * 256;
        int row = idx >> 4, ch = idx & 15;
        *(uint4*)(As + row * 136 + ch * 8) =
            *(const uint4*)(A + (size_t)(r0 + row) * 512 + ch * 8);
        *(uint4*)(Bs + row * 136 + ch * 8) = *(const uint4*)(B + row * 128 + ch * 8);
    }
    __syncthreads();

    // attention coefficient dots from the staged Y tile (pre-overwrite values)
    {
        int row = tid >> 1, half = tid & 1;
        const ushort_t* yr = As + row * 136 + half * 64;
        float d1 = 0.f, d2 = 0.f;
        #pragma unroll
        for (int t = 0; t < 8; ++t) {
            short8 v = *(const short8*)(yr + t * 8);
            #pragma unroll
            for (int j = 0; j < 8; ++j) {
                float f = bf2f(((const ushort_t*)&v)[j]);
                d2 += f * a2wS[half * 64 + t * 8 + j];
                d1 += f * a1wS[half * 64 + t * 8 + j];
            }
        }
        d2 += __shfl_xor(d2, 1);
        d1 += __shfl_xor(d1, 1);
        if (half == 0) {
            a2o[(size_t)h * MPAD + r0 + row] = d2 + a2b[h];
            if (l == 0) a1o[(size_t)h * P0 + r0 + row] = d1 + a1b[h];
        }
    }

    const int lane = tid & 63;
    const int wid = tid >> 6;
    const int wm = wid >> 1, wn = wid & 1;
    const int l15 = lane & 15, lg = lane >> 4;

    f32x4 acc[4][4] = {};
    #pragma unroll
    for (int kt = 0; kt < 128; kt += 32) {
        short8 af[4], bfr[4];
        #pragma unroll
        for (int m = 0; m < 4; ++m)
            af[m] = *(const short8*)(As + (wm * 64 + m * 16 + l15) * 136 + kt + lg * 8);
        #pragma unroll
        for (int n = 0; n < 4; ++n)
            bfr[n] = *(const short8*)(Bs + (wn * 64 + n * 16 + l15) * 136 + kt + lg * 8);
        #pragma unroll
        for (int m = 0; m < 4; ++m)
            #pragma unroll
            for (int n = 0; n < 4; ++n)
                acc[m][n] = __builtin_amdgcn_mfma_f32_16x16x32_bf16(af[m], bfr[n], acc[m][n], 0, 0, 0);
    }

    #pragma unroll
    for (int m = 0; m < 4; ++m)
    #pragma unroll
    for (int n = 0; n < 4; ++n)
    #pragma unroll
    for (int j = 0; j < 4; ++j) {
        int row = r0 + wm * 64 + m * 16 + lg * 4 + j;
        int col = wn * 64 + n * 16 + l15;
        A[(size_t)row * 512 + col] = f2bf(acc[m][n][j]);
    }
}

// ---------- out-init GEMM: 0.25*(Y0_allheads @ WgtC + bsum) -> f32 out ----------
__global__ __launch_bounds__(256)
void gemm_init(const ushort_t* __restrict__ A,
               const ushort_t* __restrict__ B,
               float* __restrict__ outF,
               const float* __restrict__ bias)
{
    __shared__ ushort_t As[128 * 40];
    __shared__ ushort_t Bs[128 * 40];
    const int tid = threadIdx.x;
    const int lane = tid & 63;
    const int wid = tid >> 6;
    const int wm = wid >> 1, wn = wid & 1;
    const int r0 = blockIdx.x * 128;
    const int l15 = lane & 15, lg = lane >> 4;

    f32x4 acc[4][4] = {};

    for (int kt = 0; kt < 512; kt += 32) {
        #pragma unroll
        for (int c = 0; c < 2; ++c) {
            int idx = tid + c * 256;
            int row = idx >> 2, kc = idx & 3;
            uint4 va = *(const uint4*)(A + (size_t)(r0 + row) * 512 + kt + kc * 8);
            *(uint4*)(As + row * 40 + kc * 8) = va;
            uint4 vb = *(const uint4*)(B + (size_t)row * 512 + kt + kc * 8);
            *(uint4*)(Bs + row * 40 + kc * 8) = vb;
        }
        __syncthreads();
        short8 af[4], bfr[4];
        #pragma unroll
        for (int m = 0; m < 4; ++m)
            af[m] = *(const short8*)(As + (wm * 64 + m * 16 + l15) * 40 + lg * 8);
        #pragma unroll
        for (int n = 0; n < 4; ++n)
            bfr[n] = *(const short8*)(Bs + (wn * 64 + n * 16 + l15) * 40 + lg * 8);
        #pragma unroll
        for (int m = 0; m < 4; ++m)
            #pragma unroll
            for (int n = 0; n < 4; ++n)
                acc[m][n] = __builtin_amdgcn_mfma_f32_16x16x32_bf16(af[m], bfr[n], acc[m][n], 0, 0, 0);
        __syncthreads();
    }

    #pragma unroll
    for (int m = 0; m < 4; ++m)
    #pragma unroll
    for (int n = 0; n < 4; ++n)
    #pragma unroll
    for (int j = 0; j < 4; ++j) {
        int row = r0 + wm * 64 + m * 16 + lg * 4 + j;
        int col = wn * 64 + n * 16 + l15;
        if (row < N0) outF[(size_t)row * 128 + col] = 0.25f * (acc[m][n][j] + bias[col]);
    }
}

// ---------- pull aggregation: one wave per row, no atomics, 8/4/1 gather tiers ----------
__global__ __launch_bounds__(256) void pull_agg(const int* __restrict__ rowPtr,
                                                const int* __restrict__ sortedCg,
                                                const float* __restrict__ a1,
                                                const float* __restrict__ a2,
                                                const ushort_t* __restrict__ z,
                                                float* __restrict__ out) {
    int w = blockIdx.x * 4 + (threadIdx.x >> 6);
    if (w >= N0) return;
    const int lane = threadIdx.x & 63;
    const int h = lane >> 4, g = lane & 15;

    const float a1r = a1[(size_t)h * P0 + w];
    const float* a2h = a2 + (size_t)h * MPAD;
    int beg = rowPtr[w], end = rowPtr[w + 1];

    float acc[8] = {0.f, 0.f, 0.f, 0.f, 0.f, 0.f, 0.f, 0.f};
    int e = beg;
    int cnt = end - beg;
    int n8 = beg + (cnt & ~7);
    for (; e < n8; e += 8) {
        int cg[8];
        #pragma unroll
        for (int t = 0; t < 8; ++t) cg[t] = sortedCg[e + t];
        uint4 v[8];
        #pragma unroll
        for (int t = 0; t < 8; ++t) v[t] = *(const uint4*)(z + (size_t)cg[t] * 512 + lane * 8);
        float att[8];
        #pragma unroll
        for (int t = 0; t < 8; ++t) att[t] = 0.25f / (1.f + __expf(-(a1r + a2h[cg[t]])));
        #pragma unroll
        for (int t = 0; t < 8; ++t) {
            const ushort_t* u = (const ushort_t*)&v[t];
            #pragma unroll
            for (int j = 0; j < 8; ++j) acc[j] += att[t] * bf2f(u[j]);
        }
    }
    int n4 = beg + (cnt & ~3);
    for (; e < n4; e += 4) {
        int cg0 = sortedCg[e],     cg1 = sortedCg[e + 1];
        int cg2 = sortedCg[e + 2], cg3 = sortedCg[e + 3];
        float att0 = 0.25f / (1.f + __expf(-(a1r + a2h[cg0])));
        float att1 = 0.25f / (1.f + __expf(-(a1r + a2h[cg1])));
        float att2 = 0.25f / (1.f + __expf(-(a1r + a2h[cg2])));
        float att3 = 0.25f / (1.f + __expf(-(a1r + a2h[cg3])));
        uint4 v0 = *(const uint4*)(z + (size_t)cg0 * 512 + lane * 8);
        uint4 v1 = *(const uint4*)(z + (size_t)cg1 * 512 + lane * 8);
        uint4 v2 = *(const uint4*)(z + (size_t)cg2 * 512 + lane * 8);
        uint4 v3 = *(const uint4*)(z + (size_t)cg3 * 512 + lane * 8);
        const ushort_t* u0 = (const ushort_t*)&v0;
        const ushort_t* u1 = (const ushort_t*)&v1;
        const ushort_t* u2 = (const ushort_t*)&v2;
        const ushort_t* u3 = (const ushort_t*)&v3;
        #pragma unroll
        for (int j = 0; j < 8; ++j)
            acc[j] += att0 * bf2f(u0[j]) + att1 * bf2f(u1[j])
                    + att2 * bf2f(u2[j]) + att3 * bf2f(u3[j]);
    }
    for (; e < end; ++e) {
        int cg = sortedCg[e];
        float att = 0.25f / (1.f + __expf(-(a1r + a2h[cg])));
        uint4 v = *(const uint4*)(z + (size_t)cg * 512 + lane * 8);
        const ushort_t* u = (const ushort_t*)&v;
        #pragma unroll
        for (int j = 0; j < 8; ++j) acc[j] += att * bf2f(u[j]);
    }
    #pragma unroll
    for (int j = 0; j < 8; ++j) {
        acc[j] += __shfl_xor(acc[j], 16);
        acc[j] += __shfl_xor(acc[j], 32);
    }
    float2* p = (float2*)(out + (size_t)w * 128 + g * 8 + h * 2);
    float2 o = *p;
    o.x += acc[h * 2 + 0];
    o.y += acc[h * 2 + 1];
    *p = o;
}

extern "C" void kernel_launch(void* const* d_in, const int* in_sizes, int n_in,
                              void* d_out, int out_size, void* d_ws, size_t ws_size,
                              hipStream_t stream) {
    const float* x0   = (const float*)d_in[0];
    const float* x1   = (const float*)d_in[1];
    const float* x2   = (const float*)d_in[2];
    const int* rows0  = (const int*)d_in[3];
    const int* cols0  = (const int*)d_in[4];
    const int* rows1  = (const int*)d_in[5];
    const int* cols1  = (const int*)d_in[6];
    const int* rows2  = (const int*)d_in[7];
    const int* cols2  = (const int*)d_in[8];
    const float* W1   = (const float*)d_in[9];
    const float* b1   = (const float*)d_in[10];
    const float* a1w  = (const float*)d_in[11];
    const float* a1b  = (const float*)d_in[12];
    const float* a2w  = (const float*)d_in[13];
    const float* a2b  = (const float*)d_in[14];
    const float* Wagg = (const float*)d_in[15];
    const float* bagg = (const float*)d_in[16];
    float* out = (float*)d_out;
    char* ws = (char*)d_ws;

    // workspace layout — total 194,853,632 B (r4-proven size)
    ushort_t* Y      = (ushort_t*)(ws);               // [MPAD][512] bf16 (becomes Z in place)
    float*    a1o    = (float*)(ws + 184680448);
    float*    a2o    = (float*)(ws + 185163776);
    ushort_t* W1t    = (ushort_t*)(ws + 188049408);
    ushort_t* Wgt    = (ushort_t*)(ws + 188311552);
    ushort_t* WgtC   = (ushort_t*)(ws + 188704768);
    float*    bsum   = (float*)(ws + 188835840);
    int*      cur    = (int*)(ws + 188836352);
    int*      rowPtr = (int*)(ws + 189204992);
    int*      srtCg  = (int*)(ws + 189573632);

    int* rp0  = rowPtr, * rp1  = rowPtr + CSTRIDE, * rp2  = rowPtr + 2 * CSTRIDE;
    int* srt0 = srtCg,  * srt1 = srtCg + NE0,      * srt2 = srtCg + NE0 + NE1;

    // 1) per-level CSR build (merged launches)
    csr_zero<<<(3 * CSTRIDE + 255) / 256, 256, 0, stream>>>(cur);
    csr_hist_all<<<(NNZ_ALL + 255) / 256, 256, 0, stream>>>(rows0, rows1, rows2, cur);
    csr_scan<<<3, 1024, 0, stream>>>(cur, rowPtr, NE0, NE1, NE2);
    csr_scatter_all<<<(NNZ_ALL + 255) / 256, 256, 0, stream>>>(
        rows0, cols0, rows1, cols1, rows2, cols2, cur, srtCg);

    // 2) weight prep + Y = relu(x @ W1 + b1)
    prep_w<<<768, 256, 0, stream>>>(W1, Wagg, bagg, W1t, Wgt, WgtC, bsum);
    gemm_y<<<MT64Y, 256, 0, stream>>>(x0, x1, x2, W1t, b1, Y);

    // 3) out init reads Y level 0 (pre-overwrite)
    gemm_init<<<MT0, 256, 0, stream>>>(Y, WgtC, out, bsum);

    // 4) z = Y_h @ Wg IN PLACE on Y, fused with attention-coefficient dots
    gemm_z<<<dim3(MT_ALL, 4), 256, 0, stream>>>(Y, Wgt, a1w, a1b, a2w, a2b, a1o, a2o);

    // 5) per-level pull aggregation (no atomics)
    pull_agg<<<(N0 + 3) / 4, 256, 0, stream>>>(rp0, srt0, a1o, a2o, Y, out);
    pull_agg<<<(N0 + 3) / 4, 256, 0, stream>>>(rp1, srt1, a1o, a2o, Y, out);
    pull_agg<<<(N0 + 3) / 4, 256, 0, stream>>>(rp2, srt2, a1o, a2o, Y, out);
}

// Round 16
// 613.465 us; speedup vs baseline: 1.0187x; 1.0187x over previous
//
#include <hip/hip_runtime.h>

typedef __attribute__((ext_vector_type(8))) short short8;
typedef __attribute__((ext_vector_type(4))) float f32x4;
typedef unsigned short ushort_t;
typedef unsigned int uint32;

// ---------- constants ----------
#define N0 30000
#define N1 90000
#define N2 60000
#define P0 30208   // 236*128, 472*64
#define S1OFF 30208
#define S2OFF 120320
#define MPAD 180352
#define MT0 236
#define MT_ALL 1409
#define MT64Y 2818  // MPAD/64
#define NE0 960000
#define NE1 180000
#define NE2 180000
#define NNZ_ALL 1320000
#define CSTRIDE 30720  // per-level cur/rowPtr stride (>= N0+1)

__device__ __forceinline__ float bf2f(ushort_t u) {
    union { uint32 i; float f; } v; v.i = ((uint32)u) << 16; return v.f;
}
__device__ __forceinline__ ushort_t f2bf(float f) {
    union { float f; uint32 i; } v; v.f = f;
    uint32 x = v.i;
    x += ((x >> 16) & 1u) + 0x7FFFu;   // RNE
    return (ushort_t)(x >> 16);
}

// ---------- prep: weights -> bf16 transposed layouts ----------
__global__ __launch_bounds__(256) void prep_w(const float* __restrict__ W1,
                                              const float* __restrict__ Wagg,
                                              const float* __restrict__ bagg,
                                              ushort_t* __restrict__ W1t,   // [4][128][256]
                                              ushort_t* __restrict__ Wgt,   // [4][3][128][128]
                                              ushort_t* __restrict__ WgtC,  // [128][512]
                                              float* __restrict__ bsum) {   // [128]
    int idx = blockIdx.x * blockDim.x + threadIdx.x;
    if (idx < 131072) {  // W1t[h][n][k] = W1[h][k][n]
        int h = idx >> 15, rem = idx & 32767, n = rem >> 8, k = rem & 255;
        W1t[idx] = f2bf(W1[((size_t)h * 256 + k) * 128 + n]);
    }
    if (idx < 196608) {  // Wgt[h][l][n][k] = Wagg[h][(l+1)*128+k][n]
        int h = idx / 49152, rem = idx % 49152;
        int l = rem / 16384, rem2 = rem % 16384, n = rem2 >> 7, k = rem2 & 127;
        Wgt[idx] = f2bf(Wagg[((size_t)h * 512 + (l + 1) * 128 + k) * 128 + n]);
    }
    if (idx < 65536) {   // WgtC[n][h*128+k] = Wagg[h][k][n]  (block 0)
        int n = idx >> 9, kk = idx & 511, h = kk >> 7, k = kk & 127;
        WgtC[idx] = f2bf(Wagg[((size_t)h * 512 + k) * 128 + n]);
    }
    if (idx < 128) {
        float s = 0.f;
        #pragma unroll
        for (int h = 0; h < 4; ++h) s += bagg[h * 128 + idx];
        bsum[idx] = s;
    }
}

// ---------- CSR build (merged across levels) ----------
__global__ __launch_bounds__(256) void csr_zero(int* __restrict__ cur) {
    int i = blockIdx.x * blockDim.x + threadIdx.x;
    if (i < 3 * CSTRIDE) cur[i] = 0;
}

__global__ __launch_bounds__(256) void csr_hist_all(const int* __restrict__ rows0,
                                                    const int* __restrict__ rows1,
                                                    const int* __restrict__ rows2,
                                                    int* __restrict__ cur) {
    int i = blockIdx.x * blockDim.x + threadIdx.x;
    if (i < NE0)                 atomicAdd(cur + rows0[i], 1);
    else if (i < NE0 + NE1)      atomicAdd(cur + CSTRIDE + rows1[i - NE0], 1);
    else if (i < NNZ_ALL)        atomicAdd(cur + 2 * CSTRIDE + rows2[i - NE0 - NE1], 1);
}

__global__ __launch_bounds__(1024) void csr_scan(int* __restrict__ curA,
                                                 int* __restrict__ rowPtrA,
                                                 int nE0, int nE1, int nE2) {
    __shared__ int ssum[1024];
    const int b = blockIdx.x;
    int* cur = curA + b * CSTRIDE;
    int* rowPtr = rowPtrA + b * CSTRIDE;
    const int nE = (b == 0) ? nE0 : (b == 1 ? nE1 : nE2);
    const int t = threadIdx.x;
    const int base = t * 30;
    int loc[30];
    int s = 0;
    #pragma unroll
    for (int i = 0; i < 30; ++i) {
        int r = base + i;
        int v = (r < N0) ? cur[r] : 0;
        loc[i] = s; s += v;
    }
    ssum[t] = s;
    __syncthreads();
    for (int off = 1; off < 1024; off <<= 1) {
        int v = (t >= off) ? ssum[t - off] : 0;
        __syncthreads();
        ssum[t] += v;
        __syncthreads();
    }
    int carry = (t == 0) ? 0 : ssum[t - 1];
    #pragma unroll
    for (int i = 0; i < 30; ++i) {
        int r = base + i;
        if (r < N0) {
            int p = carry + loc[i];
            rowPtr[r] = p;
            cur[r] = p;
        }
    }
    if (t == 0) rowPtr[N0] = nE;
}

__global__ __launch_bounds__(256) void csr_scatter_all(const int* __restrict__ rows0,
                                                       const int* __restrict__ cols0,
                                                       const int* __restrict__ rows1,
                                                       const int* __restrict__ cols1,
                                                       const int* __restrict__ rows2,
                                                       const int* __restrict__ cols2,
                                                       int* __restrict__ cur,
                                                       int* __restrict__ srtCg) {
    int i = blockIdx.x * blockDim.x + threadIdx.x;
    if (i < NE0) {
        int pos = atomicAdd(cur + rows0[i], 1);
        srtCg[pos] = cols0[i];
    } else if (i < NE0 + NE1) {
        int j = i - NE0;
        int pos = atomicAdd(cur + CSTRIDE + rows1[j], 1);
        srtCg[NE0 + pos] = S1OFF + cols1[j];
    } else if (i < NNZ_ALL) {
        int j = i - NE0 - NE1;
        int pos = atomicAdd(cur + 2 * CSTRIDE + rows2[j], 1);
        srtCg[NE0 + NE1 + pos] = S2OFF + cols2[j];
    }
}

// ---------- Y = relu(X @ W1 + b1): r12-proven ----------
// grid 2818; 256 thr = 4 waves, each 64 rows x 64 consecutive cols of one head.
// As[64][256] swizzled (staged ONCE); Bs[2][128][40] per-kt head-pair staging.
__global__ __launch_bounds__(256, 3)
void gemm_y(const float* __restrict__ x0, const float* __restrict__ x1,
            const float* __restrict__ x2,
            const ushort_t* __restrict__ W1t, const float* __restrict__ b1,
            ushort_t* __restrict__ Y)
{
    __shared__ ushort_t As[64 * 256];
    __shared__ ushort_t Bs[2][128 * 40];
    const int tid = threadIdx.x;
    const int lane = tid & 63;
    const int wn = tid >> 6;                 // 0..3: col group
    const int l15 = lane & 15, lg = lane >> 4;
    const int r0 = blockIdx.x * 64;

    const float* src; int jbase, nreal;
    if (r0 < P0)          { src = x0; jbase = r0;         nreal = N0; }
    else if (r0 < S2OFF)  { src = x1; jbase = r0 - S1OFF; nreal = N1; }
    else                  { src = x2; jbase = r0 - S2OFF; nreal = N2; }

    // stage As once: 64 rows x 32 chunks (8 bf16 each), swizzled c^(row&7)
    #pragma unroll
    for (int p = 0; p < 8; ++p) {
        int chunk = tid + p * 256;
        int row = chunk >> 5, c = chunk & 31;
        int j = jbase + row;
        ushort_t o[8] __attribute__((aligned(16)));
        if (j < nreal) {
            const float4 v0 = *(const float4*)(src + (size_t)j * 256 + c * 8);
            const float4 v1 = *(const float4*)(src + (size_t)j * 256 + c * 8 + 4);
            o[0] = f2bf(v0.x); o[1] = f2bf(v0.y); o[2] = f2bf(v0.z); o[3] = f2bf(v0.w);
            o[4] = f2bf(v1.x); o[5] = f2bf(v1.y); o[6] = f2bf(v1.z); o[7] = f2bf(v1.w);
        } else {
            #pragma unroll
            for (int i = 0; i < 8; ++i) o[i] = 0;
        }
        *(uint4*)(As + row * 256 + ((c ^ (row & 7)) << 3)) = *(const uint4*)o;
    }

    const int hh = wn >> 1;                  // head within pair (wave-uniform)
    const int nbase = (wn & 1) * 64;         // col base within head

    #pragma unroll 1
    for (int hp = 0; hp < 2; ++hp) {
        f32x4 acc[4][4] = {};
        #pragma unroll 1
        for (int kt = 0; kt < 256; kt += 32) {
            __syncthreads();   // previous readers done (covers As staging on iter 0)
            // stage Bs for heads hp*2, hp*2+1: 1024 chunks, 4/thread
            #pragma unroll
            for (int q = 0; q < 4; ++q) {
                int id = tid + q * 256;
                int bh = id >> 9, rem = id & 511;
                int n = rem >> 2, c = rem & 3;
                *(uint4*)(Bs[bh] + n * 40 + c * 8) =
                    *(const uint4*)(W1t + (hp * 2 + bh) * 32768 + n * 256 + kt + c * 8);
            }
            __syncthreads();

            short8 af[4], bf[4];
            #pragma unroll
            for (int m = 0; m < 4; ++m) {
                int row = m * 16 + l15;
                af[m] = *(const short8*)(As + row * 256 + ((((kt >> 3) + lg) ^ (row & 7)) << 3));
            }
            #pragma unroll
            for (int nf = 0; nf < 4; ++nf) {
                int nrow = nbase + nf * 16 + l15;
                bf[nf] = *(const short8*)(Bs[hh] + nrow * 40 + lg * 8);
            }
            #pragma unroll
            for (int m = 0; m < 4; ++m)
                #pragma unroll
                for (int nf = 0; nf < 4; ++nf)
                    acc[m][nf] = __builtin_amdgcn_mfma_f32_16x16x32_bf16(af[m], bf[nf], acc[m][nf], 0, 0, 0);
        }
        // epilogue: wave writes 64 consecutive cols of head h -> full 128B lines
        int h = hp * 2 + hh;
        #pragma unroll
        for (int nf = 0; nf < 4; ++nf) {
            int col = nbase + nf * 16 + l15;
            float bb = b1[h * 128 + col];
            #pragma unroll
            for (int m = 0; m < 4; ++m)
            #pragma unroll
            for (int j = 0; j < 4; ++j) {
                int row = r0 + m * 16 + lg * 4 + j;
                float v = acc[m][nf][j] + bb;
                v = v > 0.f ? v : 0.f;
                Y[(size_t)row * 512 + h * 128 + col] = f2bf(v);
            }
        }
    }
}

// ---------- fused z-projection (in place on Y) + attention coefficients ----------
// r12-proven: grid (MT_ALL, 4 heads); K=128 fully staged, 2 barriers, 64 MFMAs;
// coef dots read staged pre-overwrite As, plain stores.
__global__ __launch_bounds__(256) void gemm_z(ushort_t* Y,
                                              const ushort_t* __restrict__ Wgt,
                                              const float* __restrict__ a1w,
                                              const float* __restrict__ a1b,
                                              const float* __restrict__ a2w,
                                              const float* __restrict__ a2b,
                                              float* __restrict__ a1o,   // [4][P0]
                                              float* __restrict__ a2o) { // [4][MPAD]
    __shared__ ushort_t As[128 * 136];
    __shared__ ushort_t Bs[128 * 136];
    __shared__ float a1wS[128], a2wS[128];
    const int tid = threadIdx.x;
    const int h = blockIdx.y;
    const int r0 = blockIdx.x * 128;
    const int l = (r0 < P0) ? 0 : (r0 < S2OFF ? 1 : 2);
    const ushort_t* B = Wgt + ((h * 3 + l) << 14);
    ushort_t* A = Y + (size_t)h * 128;   // col block of head h, ld 512

    if (tid < 128) {
        a1wS[tid] = a1w[h * 128 + tid];
        a2wS[tid] = a2w[h * 128 + tid];
    }
    #pragma unroll
    for (int c = 0; c < 8; ++c) {
        int idx = tid + c * 256;
        int row = idx >> 4, ch = idx & 15;
        *(uint4*)(As + row * 136 + ch * 8) =
            *(const uint4*)(A + (size_t)(r0 + row) * 512 + ch * 8);
        *(uint4*)(Bs + row * 136 + ch * 8) = *(const uint4*)(B + row * 128 + ch * 8);
    }
    __syncthreads();

    // attention coefficient dots from the staged Y tile (pre-overwrite values)
    {
        int row = tid >> 1, half = tid & 1;
        const ushort_t* yr = As + row * 136 + half * 64;
        float d1 = 0.f, d2 = 0.f;
        #pragma unroll
        for (int t = 0; t < 8; ++t) {
            short8 v = *(const short8*)(yr + t * 8);
            #pragma unroll
            for (int j = 0; j < 8; ++j) {
                float f = bf2f(((const ushort_t*)&v)[j]);
                d2 += f * a2wS[half * 64 + t * 8 + j];
                d1 += f * a1wS[half * 64 + t * 8 + j];
            }
        }
        d2 += __shfl_xor(d2, 1);
        d1 += __shfl_xor(d1, 1);
        if (half == 0) {
            a2o[(size_t)h * MPAD + r0 + row] = d2 + a2b[h];
            if (l == 0) a1o[(size_t)h * P0 + r0 + row] = d1 + a1b[h];
        }
    }

    const int lane = tid & 63;
    const int wid = tid >> 6;
    const int wm = wid >> 1, wn = wid & 1;
    const int l15 = lane & 15, lg = lane >> 4;

    f32x4 acc[4][4] = {};
    #pragma unroll
    for (int kt = 0; kt < 128; kt += 32) {
        short8 af[4], bfr[4];
        #pragma unroll
        for (int m = 0; m < 4; ++m)
            af[m] = *(const short8*)(As + (wm * 64 + m * 16 + l15) * 136 + kt + lg * 8);
        #pragma unroll
        for (int n = 0; n < 4; ++n)
            bfr[n] = *(const short8*)(Bs + (wn * 64 + n * 16 + l15) * 136 + kt + lg * 8);
        #pragma unroll
        for (int m = 0; m < 4; ++m)
            #pragma unroll
            for (int n = 0; n < 4; ++n)
                acc[m][n] = __builtin_amdgcn_mfma_f32_16x16x32_bf16(af[m], bfr[n], acc[m][n], 0, 0, 0);
    }

    #pragma unroll
    for (int m = 0; m < 4; ++m)
    #pragma unroll
    for (int n = 0; n < 4; ++n)
    #pragma unroll
    for (int j = 0; j < 4; ++j) {
        int row = r0 + wm * 64 + m * 16 + lg * 4 + j;
        int col = wn * 64 + n * 16 + l15;
        A[(size_t)row * 512 + col] = f2bf(acc[m][n][j]);
    }
}

// ---------- out-init GEMM: 0.25*(Y0_allheads @ WgtC + bsum) -> f32 out ----------
__global__ __launch_bounds__(256)
void gemm_init(const ushort_t* __restrict__ A,
               const ushort_t* __restrict__ B,
               float* __restrict__ outF,
               const float* __restrict__ bias)
{
    __shared__ ushort_t As[128 * 40];
    __shared__ ushort_t Bs[128 * 40];
    const int tid = threadIdx.x;
    const int lane = tid & 63;
    const int wid = tid >> 6;
    const int wm = wid >> 1, wn = wid & 1;
    const int r0 = blockIdx.x * 128;
    const int l15 = lane & 15, lg = lane >> 4;

    f32x4 acc[4][4] = {};

    for (int kt = 0; kt < 512; kt += 32) {
        #pragma unroll
        for (int c = 0; c < 2; ++c) {
            int idx = tid + c * 256;
            int row = idx >> 2, kc = idx & 3;
            uint4 va = *(const uint4*)(A + (size_t)(r0 + row) * 512 + kt + kc * 8);
            *(uint4*)(As + row * 40 + kc * 8) = va;
            uint4 vb = *(const uint4*)(B + (size_t)row * 512 + kt + kc * 8);
            *(uint4*)(Bs + row * 40 + kc * 8) = vb;
        }
        __syncthreads();
        short8 af[4], bfr[4];
        #pragma unroll
        for (int m = 0; m < 4; ++m)
            af[m] = *(const short8*)(As + (wm * 64 + m * 16 + l15) * 40 + lg * 8);
        #pragma unroll
        for (int n = 0; n < 4; ++n)
            bfr[n] = *(const short8*)(Bs + (wn * 64 + n * 16 + l15) * 40 + lg * 8);
        #pragma unroll
        for (int m = 0; m < 4; ++m)
            #pragma unroll
            for (int n = 0; n < 4; ++n)
                acc[m][n] = __builtin_amdgcn_mfma_f32_16x16x32_bf16(af[m], bfr[n], acc[m][n], 0, 0, 0);
        __syncthreads();
    }

    #pragma unroll
    for (int m = 0; m < 4; ++m)
    #pragma unroll
    for (int n = 0; n < 4; ++n)
    #pragma unroll
    for (int j = 0; j < 4; ++j) {
        int row = r0 + wm * 64 + m * 16 + lg * 4 + j;
        int col = wn * 64 + n * 16 + l15;
        if (row < N0) outF[(size_t)row * 128 + col] = 0.25f * (acc[m][n][j] + bias[col]);
    }
}

// ---------- pull aggregation: one wave per output row, no atomics, x4 unroll ----------
__global__ __launch_bounds__(256) void pull_agg(const int* __restrict__ rowPtr,
                                                const int* __restrict__ sortedCg,
                                                const float* __restrict__ a1,
                                                const float* __restrict__ a2,
                                                const ushort_t* __restrict__ z,
                                                float* __restrict__ out) {
    int w = blockIdx.x * 4 + (threadIdx.x >> 6);
    if (w >= N0) return;
    const int lane = threadIdx.x & 63;
    const int h = lane >> 4, g = lane & 15;

    const float a1r = a1[(size_t)h * P0 + w];
    const float* a2h = a2 + (size_t)h * MPAD;
    int beg = rowPtr[w], end = rowPtr[w + 1];

    float acc[8] = {0.f, 0.f, 0.f, 0.f, 0.f, 0.f, 0.f, 0.f};
    int e = beg;
    int n4 = beg + ((end - beg) & ~3);
    for (; e < n4; e += 4) {
        int cg0 = sortedCg[e],     cg1 = sortedCg[e + 1];
        int cg2 = sortedCg[e + 2], cg3 = sortedCg[e + 3];
        float att0 = 0.25f / (1.f + __expf(-(a1r + a2h[cg0])));
        float att1 = 0.25f / (1.f + __expf(-(a1r + a2h[cg1])));
        float att2 = 0.25f / (1.f + __expf(-(a1r + a2h[cg2])));
        float att3 = 0.25f / (1.f + __expf(-(a1r + a2h[cg3])));
        uint4 v0 = *(const uint4*)(z + (size_t)cg0 * 512 + lane * 8);
        uint4 v1 = *(const uint4*)(z + (size_t)cg1 * 512 + lane * 8);
        uint4 v2 = *(const uint4*)(z + (size_t)cg2 * 512 + lane * 8);
        uint4 v3 = *(const uint4*)(z + (size_t)cg3 * 512 + lane * 8);
        const ushort_t* u0 = (const ushort_t*)&v0;
        const ushort_t* u1 = (const ushort_t*)&v1;
        const ushort_t* u2 = (const ushort_t*)&v2;
        const ushort_t* u3 = (const ushort_t*)&v3;
        #pragma unroll
        for (int j = 0; j < 8; ++j)
            acc[j] += att0 * bf2f(u0[j]) + att1 * bf2f(u1[j])
                    + att2 * bf2f(u2[j]) + att3 * bf2f(u3[j]);
    }
    for (; e < end; ++e) {
        int cg = sortedCg[e];
        float att = 0.25f / (1.f + __expf(-(a1r + a2h[cg])));
        uint4 v = *(const uint4*)(z + (size_t)cg * 512 + lane * 8);
        const ushort_t* u = (const ushort_t*)&v;
        #pragma unroll
        for (int j = 0; j < 8; ++j) acc[j] += att * bf2f(u[j]);
    }
    #pragma unroll
    for (int j = 0; j < 8; ++j) {
        acc[j] += __shfl_xor(acc[j], 16);
        acc[j] += __shfl_xor(acc[j], 32);
    }
    float2* p = (float2*)(out + (size_t)w * 128 + g * 8 + h * 2);
    float2 o = *p;
    o.x += acc[h * 2 + 0];
    o.y += acc[h * 2 + 1];
    *p = o;
}

extern "C" void kernel_launch(void* const* d_in, const int* in_sizes, int n_in,
                              void* d_out, int out_size, void* d_ws, size_t ws_size,
                              hipStream_t stream) {
    const float* x0   = (const float*)d_in[0];
    const float* x1   = (const float*)d_in[1];
    const float* x2   = (const float*)d_in[2];
    const int* rows0  = (const int*)d_in[3];
    const int* cols0  = (const int*)d_in[4];
    const int* rows1  = (const int*)d_in[5];
    const int* cols1  = (const int*)d_in[6];
    const int* rows2  = (const int*)d_in[7];
    const int* cols2  = (const int*)d_in[8];
    const float* W1   = (const float*)d_in[9];
    const float* b1   = (const float*)d_in[10];
    const float* a1w  = (const float*)d_in[11];
    const float* a1b  = (const float*)d_in[12];
    const float* a2w  = (const float*)d_in[13];
    const float* a2b  = (const float*)d_in[14];
    const float* Wagg = (const float*)d_in[15];
    const float* bagg = (const float*)d_in[16];
    float* out = (float*)d_out;
    char* ws = (char*)d_ws;

    // workspace layout — total 194,853,632 B (r4-proven size)
    ushort_t* Y      = (ushort_t*)(ws);               // [MPAD][512] bf16 (becomes Z in place)
    float*    a1o    = (float*)(ws + 184680448);
    float*    a2o    = (float*)(ws + 185163776);
    ushort_t* W1t    = (ushort_t*)(ws + 188049408);
    ushort_t* Wgt    = (ushort_t*)(ws + 188311552);
    ushort_t* WgtC   = (ushort_t*)(ws + 188704768);
    float*    bsum   = (float*)(ws + 188835840);
    int*      cur    = (int*)(ws + 188836352);
    int*      rowPtr = (int*)(ws + 189204992);
    int*      srtCg  = (int*)(ws + 189573632);

    int* rp0  = rowPtr, * rp1  = rowPtr + CSTRIDE, * rp2  = rowPtr + 2 * CSTRIDE;
    int* srt0 = srtCg,  * srt1 = srtCg + NE0,      * srt2 = srtCg + NE0 + NE1;

    // 1) per-level CSR build (merged launches)
    csr_zero<<<(3 * CSTRIDE + 255) / 256, 256, 0, stream>>>(cur);
    csr_hist_all<<<(NNZ_ALL + 255) / 256, 256, 0, stream>>>(rows0, rows1, rows2, cur);
    csr_scan<<<3, 1024, 0, stream>>>(cur, rowPtr, NE0, NE1, NE2);
    csr_scatter_all<<<(NNZ_ALL + 255) / 256, 256, 0, stream>>>(
        rows0, cols0, rows1, cols1, rows2, cols2, cur, srtCg);

    // 2) weight prep + Y = relu(x @ W1 + b1)
    prep_w<<<768, 256, 0, stream>>>(W1, Wagg, bagg, W1t, Wgt, WgtC, bsum);
    gemm_y<<<MT64Y, 256, 0, stream>>>(x0, x1, x2, W1t, b1, Y);

    // 3) out init reads Y level 0 (pre-overwrite)
    gemm_init<<<MT0, 256, 0, stream>>>(Y, WgtC, out, bsum);

    // 4) z = Y_h @ Wg IN PLACE on Y, fused with attention-coefficient dots
    gemm_z<<<dim3(MT_ALL, 4), 256, 0, stream>>>(Y, Wgt, a1w, a1b, a2w, a2b, a1o, a2o);

    // 5) per-level pull aggregation (no atomics)
    pull_agg<<<(N0 + 3) / 4, 256, 0, stream>>>(rp0, srt0, a1o, a2o, Y, out);
    pull_agg<<<(N0 + 3) / 4, 256, 0, stream>>>(rp1, srt1, a1o, a2o, Y, out);
    pull_agg<<<(N0 + 3) / 4, 256, 0, stream>>>(rp2, srt2, a1o, a2o, Y, out);
}